// Round 1
// baseline (254.839 us; speedup 1.0000x reference)
//
#include <hip/hip_runtime.h>

// ROI bilinear pooling (tf.image.resize half-pixel centers), POOL=7.
// img: (1, 64, 64, 1024) fp32, NHWC. rois: (1, R, 4) int32 = [x, y, w, h].
// out: (1, R, 7, 7, 1024) fp32.
//
// One block per output cell (r, py, px). 256 threads x float4 = 1024 channels.
// Memory-bound on the 205 MB output write; image (16.8 MB) lives in L2/L3.

#define POOLSZ 7
#define IMG_H 64
#define IMG_W 64
#define IMG_C 1024

__global__ __launch_bounds__(256) void roi_pool_kernel(
    const float* __restrict__ img,
    const int* __restrict__ rois,
    float* __restrict__ out) {
    const int cell = blockIdx.x;               // r*49 + py*7 + px
    const int px = cell % POOLSZ;
    const int py = (cell / POOLSZ) % POOLSZ;
    const int r  = cell / (POOLSZ * POOLSZ);

    // ROI box (uniform per block; scalar unit handles this)
    const int4 roi = ((const int4*)rois)[r];
    const int rx = roi.x, ry = roi.y, rw = roi.z, rh = roi.w;

    // y-axis coords: src = (py+0.5)*h/7 - 0.5; lerp BEFORE clipping (matches ref)
    const float scy  = (float)rh * (1.0f / (float)POOLSZ);
    const float srcy = ((float)py + 0.5f) * scy - 0.5f;
    const float fy   = floorf(srcy);
    const float ty   = srcy - fy;
    const int   iy   = (int)fy;
    const int   y0   = ry + min(max(iy,     0), rh - 1);
    const int   y1   = ry + min(max(iy + 1, 0), rh - 1);

    const float scx  = (float)rw * (1.0f / (float)POOLSZ);
    const float srcx = ((float)px + 0.5f) * scx - 0.5f;
    const float fx   = floorf(srcx);
    const float tx   = srcx - fx;
    const int   ix   = (int)fx;
    const int   x0   = rx + min(max(ix,     0), rw - 1);
    const int   x1   = rx + min(max(ix + 1, 0), rw - 1);

    // Bilinear weights, composed exactly like the reference:
    // out = (a*(1-tx) + b*tx)*(1-ty) + (c*(1-tx) + d*tx)*ty
    const int c4 = threadIdx.x;  // 0..255, one float4 of channels each

    const float4* p00 = (const float4*)(img + ((size_t)y0 * IMG_W + x0) * IMG_C) + c4;
    const float4* p01 = (const float4*)(img + ((size_t)y0 * IMG_W + x1) * IMG_C) + c4;
    const float4* p10 = (const float4*)(img + ((size_t)y1 * IMG_W + x0) * IMG_C) + c4;
    const float4* p11 = (const float4*)(img + ((size_t)y1 * IMG_W + x1) * IMG_C) + c4;

    const float4 a = *p00;
    const float4 b = *p01;
    const float4 c = *p10;
    const float4 d = *p11;

    float4 top, bot, o;
    top.x = a.x + (b.x - a.x) * tx;  // a*(1-tx)+b*tx, fused form is fine in fp32
    top.y = a.y + (b.y - a.y) * tx;
    top.z = a.z + (b.z - a.z) * tx;
    top.w = a.w + (b.w - a.w) * tx;
    bot.x = c.x + (d.x - c.x) * tx;
    bot.y = c.y + (d.y - c.y) * tx;
    bot.z = c.z + (d.z - c.z) * tx;
    bot.w = c.w + (d.w - c.w) * tx;
    o.x = top.x + (bot.x - top.x) * ty;
    o.y = top.y + (bot.y - top.y) * ty;
    o.z = top.z + (bot.z - top.z) * ty;
    o.w = top.w + (bot.w - top.w) * ty;

    ((float4*)out)[(size_t)cell * (IMG_C / 4) + c4] = o;
}

extern "C" void kernel_launch(void* const* d_in, const int* in_sizes, int n_in,
                              void* d_out, int out_size, void* d_ws, size_t ws_size,
                              hipStream_t stream) {
    const float* img  = (const float*)d_in[0];
    const int*   rois = (const int*)d_in[1];
    float*       out  = (float*)d_out;
    const int R = in_sizes[1] / 4;                  // rois: (1, R, 4)
    const int n_cells = R * POOLSZ * POOLSZ;        // 1024*49 = 50176 blocks
    roi_pool_kernel<<<n_cells, 256, 0, stream>>>(img, rois, out);
}

// Round 2
// 241.159 us; speedup vs baseline: 1.0567x; 1.0567x over previous
//
#include <hip/hip_runtime.h>

// ROI bilinear pooling (tf.image.resize half-pixel centers), POOL=7.
// img: (1, 64, 64, 1024) fp32, NHWC. rois: (1, R, 4) int32 = [x, y, w, h].
// out: (1, R, 7, 7, 1024) fp32.
//
// One block per output cell (r, py, px). 256 threads x float4 = 1024 channels.
// R1 changes:
//  - XCD-aware swizzle: all 49 cells of an ROI map to one XCD (blockIdx&7),
//    so the ROI's shared source pixels stay resident in that XCD's 4MB L2
//    instead of being re-fetched from Infinity Cache by all 8 XCDs.
//  - Nontemporal output stores: 205MB write-once stream must not evict the
//    image from L2.

#define POOLSZ 7
#define IMG_H 64
#define IMG_W 64
#define IMG_C 1024
#define NUM_XCD 8

typedef float v4f __attribute__((ext_vector_type(4)));

__global__ __launch_bounds__(256) void roi_pool_kernel(
    const float* __restrict__ img,
    const int* __restrict__ rois,
    float* __restrict__ out,
    int roisPerXcd) {            // R/8 when R%8==0, else 0 (identity mapping)
    int r, cell;
    if (roisPerXcd > 0) {
        // Workgroups dispatch round-robin across XCDs: xcd = blockIdx % 8.
        // Give each XCD a contiguous chunk of ROIs; within an XCD, walk
        // ROI-by-ROI so one ROI's 49 cells run back-to-back on that XCD.
        const int xcd   = blockIdx.x & (NUM_XCD - 1);
        const int local = blockIdx.x >> 3;           // 0 .. R/8*49-1
        r    = xcd * roisPerXcd + local / (POOLSZ * POOLSZ);
        cell = local % (POOLSZ * POOLSZ);
    } else {
        r    = blockIdx.x / (POOLSZ * POOLSZ);
        cell = blockIdx.x % (POOLSZ * POOLSZ);
    }
    const int px = cell % POOLSZ;
    const int py = cell / POOLSZ;

    const int4 roi = ((const int4*)rois)[r];
    const int rx = roi.x, ry = roi.y, rw = roi.z, rh = roi.w;

    // src = (p+0.5)*size/7 - 0.5; lerp weight from unclipped floor (matches ref)
    const float scy  = (float)rh * (1.0f / (float)POOLSZ);
    const float srcy = ((float)py + 0.5f) * scy - 0.5f;
    const float fy   = floorf(srcy);
    const float ty   = srcy - fy;
    const int   iy   = (int)fy;
    const int   y0   = ry + min(max(iy,     0), rh - 1);
    const int   y1   = ry + min(max(iy + 1, 0), rh - 1);

    const float scx  = (float)rw * (1.0f / (float)POOLSZ);
    const float srcx = ((float)px + 0.5f) * scx - 0.5f;
    const float fx   = floorf(srcx);
    const float tx   = srcx - fx;
    const int   ix   = (int)fx;
    const int   x0   = rx + min(max(ix,     0), rw - 1);
    const int   x1   = rx + min(max(ix + 1, 0), rw - 1);

    const int c4 = threadIdx.x;  // 0..255, one float4 of channels each

    const v4f* p00 = (const v4f*)(img + ((size_t)y0 * IMG_W + x0) * IMG_C) + c4;
    const v4f* p01 = (const v4f*)(img + ((size_t)y0 * IMG_W + x1) * IMG_C) + c4;
    const v4f* p10 = (const v4f*)(img + ((size_t)y1 * IMG_W + x0) * IMG_C) + c4;
    const v4f* p11 = (const v4f*)(img + ((size_t)y1 * IMG_W + x1) * IMG_C) + c4;

    const v4f a = *p00;
    const v4f b = *p01;
    const v4f c = *p10;
    const v4f d = *p11;

    // out = (a*(1-tx)+b*tx)*(1-ty) + (c*(1-tx)+d*tx)*ty
    const v4f top = a + (b - a) * tx;
    const v4f bot = c + (d - c) * tx;
    const v4f o   = top + (bot - top) * ty;

    v4f* dst = (v4f*)out + ((size_t)r * (POOLSZ * POOLSZ) + cell) * (IMG_C / 4) + c4;
    __builtin_nontemporal_store(o, dst);
}

extern "C" void kernel_launch(void* const* d_in, const int* in_sizes, int n_in,
                              void* d_out, int out_size, void* d_ws, size_t ws_size,
                              hipStream_t stream) {
    const float* img  = (const float*)d_in[0];
    const int*   rois = (const int*)d_in[1];
    float*       out  = (float*)d_out;
    const int R = in_sizes[1] / 4;                       // rois: (1, R, 4)
    const int n_cells = R * POOLSZ * POOLSZ;             // 1024*49 = 50176 blocks
    const int roisPerXcd = (R % NUM_XCD == 0) ? (R / NUM_XCD) : 0;
    roi_pool_kernel<<<n_cells, 256, 0, stream>>>(img, rois, out, roisPerXcd);
}

// Round 3
// 239.085 us; speedup vs baseline: 1.0659x; 1.0087x over previous
//
#include <hip/hip_runtime.h>

// ROI bilinear pooling (tf.image.resize half-pixel centers), POOL=7.
// img: (1, 64, 64, 1024) fp32, NHWC. rois: (1, R, 4) int32 = [x, y, w, h].
// out: (1, R, 7, 7, 1024) fp32.
//
// R2 structure: one block per (roi, py) ROW (7 output cells). 256 threads,
// each owns a float4 channel slice and issues all 28 pixel loads up-front
// (7 cells x 4 bilinear taps) for deep MLP, then blends and NT-stores the
// 7 outputs. Duplicate columns across adjacent cells hit L1 within the block.
//  - XCD swizzle: all rows of an ROI -> same XCD (blockIdx&7) for L2 reuse.
//  - NT stores: 205MB write-once stream must not evict the image from L2.
//  - __launch_bounds__(256,1): allow ~150+ VGPRs, no spill.

#define POOLSZ 7
#define IMG_H 64
#define IMG_W 64
#define IMG_C 1024
#define NUM_XCD 8

typedef float v4f __attribute__((ext_vector_type(4)));

__global__ __launch_bounds__(256, 1) void roi_pool_row_kernel(
    const float* __restrict__ img,
    const int* __restrict__ rois,
    float* __restrict__ out,
    int roisPerXcd) {            // R/8 when R%8==0, else 0 (identity mapping)
    int r, py;
    if (roisPerXcd > 0) {
        // Workgroups dispatch round-robin across XCDs: xcd = blockIdx % 8.
        // Chunk ROIs per XCD; within an XCD walk ROI-by-ROI, row-by-row.
        const int xcd   = blockIdx.x & (NUM_XCD - 1);
        const int local = blockIdx.x >> 3;           // 0 .. R/8*7-1
        r  = xcd * roisPerXcd + local / POOLSZ;
        py = local % POOLSZ;
    } else {
        r  = blockIdx.x / POOLSZ;
        py = blockIdx.x % POOLSZ;
    }

    const int4 roi = ((const int4*)rois)[r];
    const int rx = roi.x, ry = roi.y, rw = roi.z, rh = roi.w;

    // y coords: src = (py+0.5)*h/7 - 0.5; lerp from unclipped floor (ref semantics)
    const float scy  = (float)rh * (1.0f / (float)POOLSZ);
    const float srcy = ((float)py + 0.5f) * scy - 0.5f;
    const float fy   = floorf(srcy);
    const float ty   = srcy - fy;
    const int   iy   = (int)fy;
    const int   y0   = ry + min(max(iy,     0), rh - 1);
    const int   y1   = ry + min(max(iy + 1, 0), rh - 1);

    // x coords for all 7 cells
    int   x0[POOLSZ], x1[POOLSZ];
    float tx[POOLSZ];
    const float scx = (float)rw * (1.0f / (float)POOLSZ);
#pragma unroll
    for (int px = 0; px < POOLSZ; ++px) {
        const float srcx = ((float)px + 0.5f) * scx - 0.5f;
        const float fx   = floorf(srcx);
        tx[px] = srcx - fx;
        const int ix = (int)fx;
        x0[px] = rx + min(max(ix,     0), rw - 1);
        x1[px] = rx + min(max(ix + 1, 0), rw - 1);
    }

    const int c4 = threadIdx.x;  // 0..255: float4 channel slice
    const v4f* row0 = (const v4f*)(img + (size_t)y0 * IMG_W * IMG_C) + c4;
    const v4f* row1 = (const v4f*)(img + (size_t)y1 * IMG_W * IMG_C) + c4;

    // Issue all 28 loads before any arithmetic (deep MLP).
    v4f a[POOLSZ], b[POOLSZ], c[POOLSZ], d[POOLSZ];
#pragma unroll
    for (int px = 0; px < POOLSZ; ++px) {
        a[px] = row0[(size_t)x0[px] * (IMG_C / 4)];
        b[px] = row0[(size_t)x1[px] * (IMG_C / 4)];
        c[px] = row1[(size_t)x0[px] * (IMG_C / 4)];
        d[px] = row1[(size_t)x1[px] * (IMG_C / 4)];
    }

    // out = (a*(1-tx)+b*tx)*(1-ty) + (c*(1-tx)+d*tx)*ty
    v4f* dst = (v4f*)out + ((size_t)r * POOLSZ + py) * POOLSZ * (IMG_C / 4) + c4;
#pragma unroll
    for (int px = 0; px < POOLSZ; ++px) {
        const v4f top = a[px] + (b[px] - a[px]) * tx[px];
        const v4f bot = c[px] + (d[px] - c[px]) * tx[px];
        const v4f o   = top + (bot - top) * ty;
        __builtin_nontemporal_store(o, dst + (size_t)px * (IMG_C / 4));
    }
}

extern "C" void kernel_launch(void* const* d_in, const int* in_sizes, int n_in,
                              void* d_out, int out_size, void* d_ws, size_t ws_size,
                              hipStream_t stream) {
    const float* img  = (const float*)d_in[0];
    const int*   rois = (const int*)d_in[1];
    float*       out  = (float*)d_out;
    const int R = in_sizes[1] / 4;                  // rois: (1, R, 4)
    const int n_rows = R * POOLSZ;                  // 1024*7 = 7168 blocks
    const int roisPerXcd = (R % NUM_XCD == 0) ? (R / NUM_XCD) : 0;
    roi_pool_row_kernel<<<n_rows, 256, 0, stream>>>(img, rois, out, roisPerXcd);
}